// Round 1
// baseline (944.129 us; speedup 1.0000x reference)
//
#include <hip/hip_runtime.h>
#include <math.h>

#define FDIM 128
#define F3   384

static constexpr int K1_R = 16;   // rows per block, context net
static constexpr int K2_R = 16;   // rows per block, v@Wmix ctx
static constexpr int K4_R = 8;    // rows per block, epilogue

// ---------------------------------------------------------------------------
// Kernel 1: X = silu(H @ W1 + b1) @ W2 + b2        [N, 3F]
// One block = 128 threads (thread = output channel f), K1_R atoms per block.
// W1/W2 read once per block from L2 (amortized over K1_R rows).
// ---------------------------------------------------------------------------
__global__ __launch_bounds__(128) void k1_ctxnet(
    const float* __restrict__ H,  const float* __restrict__ W1,
    const float* __restrict__ b1, const float* __restrict__ W2,
    const float* __restrict__ b2, float* __restrict__ X, int N)
{
    __shared__ float sH[K1_R][FDIM];
    __shared__ float sT[K1_R][FDIM];
    const int f  = threadIdx.x;
    const int n0 = blockIdx.x * K1_R;

    for (int r = 0; r < K1_R; ++r) {
        int n = n0 + r;
        sH[r][f] = (n < N) ? H[(size_t)n * FDIM + f] : 0.f;
    }
    __syncthreads();

    float acc[K1_R];
    #pragma unroll
    for (int r = 0; r < K1_R; ++r) acc[r] = 0.f;
    for (int a = 0; a < FDIM; ++a) {
        float w = W1[a * FDIM + f];
        #pragma unroll
        for (int r = 0; r < K1_R; ++r) acc[r] = fmaf(sH[r][a], w, acc[r]);
    }
    float bb = b1[f];
    #pragma unroll
    for (int r = 0; r < K1_R; ++r) {
        float t = acc[r] + bb;
        sT[r][f] = t / (1.f + expf(-t));   // silu
    }
    __syncthreads();

    float a0[K1_R], a1[K1_R], a2[K1_R];
    #pragma unroll
    for (int r = 0; r < K1_R; ++r) { a0[r] = 0.f; a1[r] = 0.f; a2[r] = 0.f; }
    for (int a = 0; a < FDIM; ++a) {
        float w0 = W2[a * F3 + f];
        float w1 = W2[a * F3 + FDIM + f];
        float w2 = W2[a * F3 + 2 * FDIM + f];
        #pragma unroll
        for (int r = 0; r < K1_R; ++r) {
            float t = sT[r][a];
            a0[r] = fmaf(t, w0, a0[r]);
            a1[r] = fmaf(t, w1, a1[r]);
            a2[r] = fmaf(t, w2, a2[r]);
        }
    }
    float c0 = b2[f], c1 = b2[FDIM + f], c2 = b2[2 * FDIM + f];
    for (int r = 0; r < K1_R; ++r) {
        int n = n0 + r;
        if (n < N) {
            X[(size_t)n * F3 + f]            = a0[r] + c0;
            X[(size_t)n * F3 + FDIM + f]     = a1[r] + c1;
            X[(size_t)n * F3 + 2 * FDIM + f] = a2[r] + c2;
        }
    }
}

// ---------------------------------------------------------------------------
// Kernel 2: ctx[n,f] = sum_d (v[n,d,:] @ Wmix[:, f]) * (v[n,d,:] @ Wmix[:, F+f])
// d-outer loop keeps live accumulators at 2*K2_R; Wmix re-read 3x from L2.
// ---------------------------------------------------------------------------
__global__ __launch_bounds__(128) void k2_ctx(
    const float* __restrict__ v, const float* __restrict__ Wmix,
    float* __restrict__ ctx, int N)
{
    __shared__ float sv[3][K2_R][FDIM];
    const int f  = threadIdx.x;
    const int n0 = blockIdx.x * K2_R;

    for (int r = 0; r < K2_R; ++r) {
        int n = n0 + r;
        for (int d = 0; d < 3; ++d)
            sv[d][r][f] = (n < N) ? v[((size_t)n * 3 + d) * FDIM + f] : 0.f;
    }
    __syncthreads();

    float cacc[K2_R];
    #pragma unroll
    for (int r = 0; r < K2_R; ++r) cacc[r] = 0.f;

    for (int d = 0; d < 3; ++d) {
        float aV[K2_R], aW[K2_R];
        #pragma unroll
        for (int r = 0; r < K2_R; ++r) { aV[r] = 0.f; aW[r] = 0.f; }
        for (int a = 0; a < FDIM; ++a) {
            float w0 = Wmix[a * (2 * FDIM) + f];
            float w1 = Wmix[a * (2 * FDIM) + FDIM + f];
            #pragma unroll
            for (int r = 0; r < K2_R; ++r) {
                float t = sv[d][r][a];
                aV[r] = fmaf(t, w0, aV[r]);
                aW[r] = fmaf(t, w1, aW[r]);
            }
        }
        #pragma unroll
        for (int r = 0; r < K2_R; ++r) cacc[r] = fmaf(aV[r], aW[r], cacc[r]);
    }
    for (int r = 0; r < K2_R; ++r) {
        int n = n0 + r;
        if (n < N) ctx[(size_t)n * FDIM + f] = cacc[r];
    }
}

// ---------------------------------------------------------------------------
// Kernel 3: edge gather + segment reduction.
// idx_i is SORTED -> one block per destination atom, binary-search the edge
// range, accumulate in registers, direct store. Zero atomics, no zero-init.
// This kernel streams Wij (491.5 MB) and is the HBM-bound hot spot.
// ---------------------------------------------------------------------------
__device__ inline int lower_bound_i(const int* __restrict__ a, int n, int val) {
    int lo = 0, hi = n;
    while (lo < hi) {
        int m = (lo + hi) >> 1;
        if (a[m] < val) lo = m + 1; else hi = m;
    }
    return lo;
}

__global__ __launch_bounds__(128) void k3_edges(
    const float* __restrict__ X, const float* __restrict__ V,
    const float* __restrict__ Wij, const float* __restrict__ dir_ij,
    const int* __restrict__ idx_i, const int* __restrict__ idx_j,
    float* __restrict__ dh, float* __restrict__ dv, int E)
{
    const int n = blockIdx.x;
    const int f = threadIdx.x;
    const int e0 = lower_bound_i(idx_i, E, n);
    const int e1 = lower_bound_i(idx_i, E, n + 1);

    float adh = 0.f, adv0 = 0.f, adv1 = 0.f, adv2 = 0.f;
    for (int e = e0; e < e1; ++e) {
        const int j = idx_j[e];
        const float* wij = Wij + (size_t)e * F3;
        const float* xj  = X   + (size_t)j * F3;
        const float* vj  = V   + (size_t)j * F3;
        float w0 = wij[f], w1 = wij[FDIM + f], w2 = wij[2 * FDIM + f];
        float x0 = xj[f],  x1 = xj[FDIM + f],  x2 = xj[2 * FDIM + f];
        float vd0 = vj[f], vd1 = vj[FDIM + f], vd2 = vj[2 * FDIM + f];
        float d0 = dir_ij[3 * (size_t)e + 0];
        float d1 = dir_ij[3 * (size_t)e + 1];
        float d2 = dir_ij[3 * (size_t)e + 2];
        adh = fmaf(w0, x0, adh);
        float dvR = w1 * x1;
        float dvv = w2 * x2;
        adv0 = fmaf(dvR, d0, fmaf(dvv, vd0, adv0));
        adv1 = fmaf(dvR, d1, fmaf(dvv, vd1, adv1));
        adv2 = fmaf(dvR, d2, fmaf(dvv, vd2, adv2));
    }
    dh[(size_t)n * FDIM + f]            = adh;
    dv[(size_t)n * F3 + f]              = adv0;
    dv[(size_t)n * F3 + FDIM + f]       = adv1;
    dv[(size_t)n * F3 + 2 * FDIM + f]   = adv2;
}

// ---------------------------------------------------------------------------
// Kernel 4: epilogue.
// q  = LN(h + dh@Whr + (dh@Whf)*ctx) * gamma + beta
// mu = (v*(1+dh.Wvr) + dv) / rms
// ---------------------------------------------------------------------------
__device__ inline float block_reduce_sum_128(float val, float* tmp) {
    #pragma unroll
    for (int o = 32; o > 0; o >>= 1) val += __shfl_down(val, o, 64);
    const int tid = threadIdx.x;
    if ((tid & 63) == 0) tmp[tid >> 6] = val;
    __syncthreads();
    float r = tmp[0] + tmp[1];
    __syncthreads();
    return r;
}

__global__ __launch_bounds__(128) void k4_epilogue(
    const float* __restrict__ h,   const float* __restrict__ v,
    const float* __restrict__ dh,  const float* __restrict__ dv,
    const float* __restrict__ ctx,
    const float* __restrict__ Whr, const float* __restrict__ Whf,
    const float* __restrict__ Wvr,
    const float* __restrict__ gamma, const float* __restrict__ beta,
    float* __restrict__ q, float* __restrict__ mu, int N)
{
    __shared__ float sdh[K4_R][FDIM];
    __shared__ float sred[2];
    const int f  = threadIdx.x;
    const int n0 = blockIdx.x * K4_R;

    for (int r = 0; r < K4_R; ++r) {
        int n = n0 + r;
        sdh[r][f] = (n < N) ? dh[(size_t)n * FDIM + f] : 0.f;
    }
    __syncthreads();

    float accR[K4_R], accF[K4_R];
    #pragma unroll
    for (int r = 0; r < K4_R; ++r) { accR[r] = 0.f; accF[r] = 0.f; }
    for (int a = 0; a < FDIM; ++a) {
        float wr = Whr[a * FDIM + f];
        float wf = Whf[a * FDIM + f];
        #pragma unroll
        for (int r = 0; r < K4_R; ++r) {
            accR[r] = fmaf(sdh[r][a], wr, accR[r]);
            accF[r] = fmaf(sdh[r][a], wf, accF[r]);
        }
    }

    const float wv = Wvr[f];
    const float g  = gamma[f];
    const float bt = beta[f];

    for (int r = 0; r < K4_R; ++r) {
        int n = n0 + r;
        if (n >= N) break;   // uniform across block (n0+r identical for all threads)

        // s = dh . Wvr   (scalar per atom)
        float s = block_reduce_sum_128(sdh[r][f] * wv, sred);

        // LayerNorm path
        float u    = h[(size_t)n * FDIM + f] + accR[r] + accF[r] * ctx[(size_t)n * FDIM + f];
        float mean = block_reduce_sum_128(u, sred) * (1.f / 128.f);
        float dlt  = u - mean;
        float var  = block_reduce_sum_128(dlt * dlt, sred) * (1.f / 128.f);
        q[(size_t)n * FDIM + f] = dlt * rsqrtf(var + 1e-5f) * g + bt;

        // Equivariant RMS-norm path
        float sc = 1.f + s;
        float x0 = fmaf(v[((size_t)n * 3 + 0) * FDIM + f], sc, dv[(size_t)n * F3 + f]);
        float x1 = fmaf(v[((size_t)n * 3 + 1) * FDIM + f], sc, dv[(size_t)n * F3 + FDIM + f]);
        float x2 = fmaf(v[((size_t)n * 3 + 2) * FDIM + f], sc, dv[(size_t)n * F3 + 2 * FDIM + f]);
        float sq  = x0 * x0 + x1 * x1 + x2 * x2;
        float tot = block_reduce_sum_128(sq, sred) * (1.f / 128.f);
        float inv = rsqrtf(tot + 1e-8f);
        mu[((size_t)n * 3 + 0) * FDIM + f] = x0 * inv;
        mu[((size_t)n * 3 + 1) * FDIM + f] = x1 * inv;
        mu[((size_t)n * 3 + 2) * FDIM + f] = x2 * inv;
    }
}

// ---------------------------------------------------------------------------
extern "C" void kernel_launch(void* const* d_in, const int* in_sizes, int n_in,
                              void* d_out, int out_size, void* d_ws, size_t ws_size,
                              hipStream_t stream)
{
    const float* h     = (const float*)d_in[0];
    const float* v     = (const float*)d_in[1];
    const float* H     = (const float*)d_in[2];
    const float* V     = (const float*)d_in[3];
    const float* Wij   = (const float*)d_in[4];
    const float* dir   = (const float*)d_in[5];
    const float* W1    = (const float*)d_in[6];
    const float* b1    = (const float*)d_in[7];
    const float* W2    = (const float*)d_in[8];
    const float* b2    = (const float*)d_in[9];
    const float* Wmix  = (const float*)d_in[10];
    const float* Whr   = (const float*)d_in[11];
    const float* Whf   = (const float*)d_in[12];
    const float* Wvr   = (const float*)d_in[13];
    const float* gamma = (const float*)d_in[14];
    const float* beta  = (const float*)d_in[15];
    const int*   idx_i = (const int*)d_in[16];
    const int*   idx_j = (const int*)d_in[17];

    const int N = in_sizes[0] / FDIM;
    const int E = in_sizes[16];

    float* ws  = (float*)d_ws;
    float* X   = ws;                         // N*384
    float* ctx = X   + (size_t)N * F3;       // N*128
    float* dh  = ctx + (size_t)N * FDIM;     // N*128
    float* dv  = dh  + (size_t)N * FDIM;     // N*384

    float* q   = (float*)d_out;              // N*128
    float* mu  = q + (size_t)N * FDIM;       // N*384

    hipLaunchKernelGGL(k1_ctxnet, dim3((N + K1_R - 1) / K1_R), dim3(128), 0, stream,
                       H, W1, b1, W2, b2, X, N);
    hipLaunchKernelGGL(k2_ctx, dim3((N + K2_R - 1) / K2_R), dim3(128), 0, stream,
                       v, Wmix, ctx, N);
    hipLaunchKernelGGL(k3_edges, dim3(N), dim3(128), 0, stream,
                       X, V, Wij, dir, idx_i, idx_j, dh, dv, E);
    hipLaunchKernelGGL(k4_epilogue, dim3((N + K4_R - 1) / K4_R), dim3(128), 0, stream,
                       h, v, dh, dv, ctx, Whr, Whf, Wvr, gamma, beta, q, mu, N);
}